// Round 11
// baseline (25.187 us; speedup 1.0000x reference)
//
#include <hip/hip_runtime.h>

constexpr int IMG_H = 2048;
constexpr int IMG_W = 2048;

// compare-exchange: a=min, b=max (2 VALU)
#define CE(a, b) {                                              \
    float _mn, _mx;                                             \
    asm("v_min_f32 %0, %1, %2" : "=v"(_mn) : "v"(a), "v"(b));   \
    asm("v_max_f32 %0, %1, %2" : "=v"(_mx) : "v"(a), "v"(b));   \
    a = _mn; b = _mx;                                           \
}

// 3-element sort via VOP3 3-input ops: a=min, b=med, c=max (3 VALU)
#define SORT3(a, b, c) {                                                      \
    float _n, _d, _x;                                                         \
    asm("v_min3_f32 %0, %1, %2, %3" : "=v"(_n) : "v"(a), "v"(b), "v"(c));     \
    asm("v_med3_f32 %0, %1, %2, %3" : "=v"(_d) : "v"(a), "v"(b), "v"(c));     \
    asm("v_max3_f32 %0, %1, %2, %3" : "=v"(_x) : "v"(a), "v"(b), "v"(c));     \
    a = _n; b = _d; c = _x;                                                   \
}

__device__ __forceinline__ void sw14(float& a0, float& a1, float& a2, float& a3, float& a4,
                                     float& a5, float& a6, float& a7, float& a8, float& a9,
                                     float& a10, float& a11, float& a12, float& a13) {
    SORT3(a0, a1, a2) SORT3(a3, a4, a5) SORT3(a6, a7, a8) SORT3(a9, a10, a11) CE(a12, a13)
    SORT3(a0, a3, a6) SORT3(a0, a9, a12)
    SORT3(a2, a5, a8) SORT3(a8, a11, a13)
}
__device__ __forceinline__ void sw13(float& a0, float& a1, float& a2, float& a3, float& a4,
                                     float& a5, float& a6, float& a7, float& a8, float& a9,
                                     float& a10, float& a11, float& a12) {
    SORT3(a0, a1, a2) SORT3(a3, a4, a5) SORT3(a6, a7, a8) SORT3(a9, a10, a11)
    SORT3(a0, a3, a6) SORT3(a0, a9, a12)
    SORT3(a2, a5, a8) SORT3(a8, a11, a12)
}
__device__ __forceinline__ void sw12(float& a0, float& a1, float& a2, float& a3, float& a4,
                                     float& a5, float& a6, float& a7, float& a8, float& a9,
                                     float& a10, float& a11) {
    SORT3(a0, a1, a2) SORT3(a3, a4, a5) SORT3(a6, a7, a8) SORT3(a9, a10, a11)
    SORT3(a0, a3, a6) CE(a0, a9)
    SORT3(a2, a5, a8) CE(a8, a11)
}
__device__ __forceinline__ void sw11(float& a0, float& a1, float& a2, float& a3, float& a4,
                                     float& a5, float& a6, float& a7, float& a8, float& a9,
                                     float& a10) {
    SORT3(a0, a1, a2) SORT3(a3, a4, a5) SORT3(a6, a7, a8) CE(a9, a10)
    SORT3(a0, a3, a6) CE(a0, a9)
    SORT3(a2, a5, a8) CE(a8, a10)
}
__device__ __forceinline__ void sw10(float& a0, float& a1, float& a2, float& a3, float& a4,
                                     float& a5, float& a6, float& a7, float& a8, float& a9) {
    SORT3(a0, a1, a2) SORT3(a3, a4, a5) SORT3(a6, a7, a8)
    SORT3(a0, a3, a6) CE(a0, a9)
    SORT3(a2, a5, a8) CE(a8, a9)
}
__device__ __forceinline__ void sw9(float& a0, float& a1, float& a2, float& a3, float& a4,
                                    float& a5, float& a6, float& a7, float& a8) {
    SORT3(a0, a1, a2) SORT3(a3, a4, a5) SORT3(a6, a7, a8)
    SORT3(a0, a3, a6)
    SORT3(a2, a5, a8)
}
__device__ __forceinline__ void sw8(float& a0, float& a1, float& a2, float& a3, float& a4,
                                    float& a5, float& a6, float& a7) {
    SORT3(a0, a1, a2) SORT3(a3, a4, a5) CE(a6, a7)
    SORT3(a0, a3, a6)
    SORT3(a2, a5, a7)
}
__device__ __forceinline__ void sw7(float& a0, float& a1, float& a2, float& a3, float& a4,
                                    float& a5, float& a6) {
    SORT3(a0, a1, a2) SORT3(a3, a4, a5)
    SORT3(a0, a3, a6)
    SORT3(a2, a5, a6)
}
__device__ __forceinline__ void sw6(float& a0, float& a1, float& a2, float& a3, float& a4,
                                    float& a5) {
    SORT3(a0, a1, a2) SORT3(a3, a4, a5)
    CE(a0, a3)
    CE(a2, a5)
}

__device__ __forceinline__ float med5(float l0, float l1, float l2, float l3, float l4) {
    CE(l0, l1) CE(l2, l3)
    float a, b;
    asm("v_max_f32 %0, %1, %2" : "=v"(a) : "v"(l0), "v"(l2));
    asm("v_min_f32 %0, %1, %2" : "=v"(b) : "v"(l1), "v"(l3));
    return __builtin_amdgcn_fmed3f(a, b, l4);
}

// tail: 8 shared survivors + 5 private values -> exact median of the 25-window
__device__ __forceinline__ float tail5(float l1, float l2, float l3, float l4, float l5,
                                       float l6, float l7, float l8,
                                       float p0, float p1, float p2, float p3, float p4) {
    float l0 = p0;
    sw9(l0, l1, l2, l3, l4, l5, l6, l7, l8);
    l0 = p1;
    sw8(l0, l1, l2, l3, l4, l5, l6, l7);
    l0 = p2;
    sw7(l0, l1, l2, l3, l4, l5, l6);
    l0 = p3;
    sw6(l0, l1, l2, l3, l4, l5);
    l0 = p4;
    return med5(l0, l1, l2, l3, l4);
}

// shared forgetful phase over 20 elements -> middle 8 (ranks 7..14), by value
__device__ __forceinline__ void shared20(float s0, float s1, float s2, float s3, float s4,
                                         float s5, float s6, float s7, float s8, float s9,
                                         float s10, float s11, float s12, float s13,
                                         float s14, float s15, float s16, float s17,
                                         float s18, float s19,
                                         float& o0, float& o1, float& o2, float& o3,
                                         float& o4, float& o5, float& o6, float& o7) {
    sw14(s0, s1, s2, s3, s4, s5, s6, s7, s8, s9, s10, s11, s12, s13);
    s0 = s14;
    sw13(s0, s1, s2, s3, s4, s5, s6, s7, s8, s9, s10, s11, s12);
    s0 = s15;
    sw12(s0, s1, s2, s3, s4, s5, s6, s7, s8, s9, s10, s11);
    s0 = s16;
    sw11(s0, s1, s2, s3, s4, s5, s6, s7, s8, s9, s10);
    s0 = s17;
    sw10(s0, s1, s2, s3, s4, s5, s6, s7, s8, s9);
    s0 = s18;
    sw9(s0, s1, s2, s3, s4, s5, s6, s7, s8);
    s0 = s19;
    o0 = s0; o1 = s1; o2 = s2; o3 = s3; o4 = s4; o5 = s5; o6 = s6; o7 = s7;
}

// Vertical pixel pair per thread: lane = image column (stride-4 coalesced loads
// and stores); pair shares rows y-1..y+2 x cols x-2..x+2 (20 elements).
__global__ __launch_bounds__(256) void median5x5_vpair(const float* __restrict__ img,
                                                       float* __restrict__ out) {
    const int x = blockIdx.x * 64 + threadIdx.x;      // image column
    const int pr = blockIdx.y * 4 + threadIdx.y;      // pair-row index
    const int yT = 2 * pr;                            // top output row

    // reflected row bases for rows yT-2 .. yT+3
    int r0 = yT - 2, r1 = yT - 1, r4 = yT + 2, r5 = yT + 3;
    r0 = (r0 < 0) ? -r0 : r0;
    r1 = (r1 < 0) ? -r1 : r1;
    r4 = (r4 >= IMG_H) ? 2 * IMG_H - 2 - r4 : r4;
    r5 = (r5 >= IMG_H) ? 2 * IMG_H - 2 - r5 : r5;
    const int b0 = r0 * IMG_W, b1 = r1 * IMG_W, b2 = yT * IMG_W,
              b3 = (yT + 1) * IMG_W, b4 = r4 * IMG_W, b5 = r5 * IMG_W;

    // reflected columns x-2 .. x+2
    int c0 = x - 2, c1 = x - 1, c3 = x + 1, c4 = x + 2;
    c0 = (c0 < 0) ? -c0 : c0;
    c1 = (c1 < 0) ? -c1 : c1;
    c3 = (c3 >= IMG_W) ? 2 * IMG_W - 2 - c3 : c3;
    c4 = (c4 >= IMG_W) ? 2 * IMG_W - 2 - c4 : c4;
    const int c2 = x;

    // 30 loads: rows A..F = yT-2 .. yT+3, cols c0..c4
    const float A0 = img[b0 + c0], A1 = img[b0 + c1], A2 = img[b0 + c2],
                A3 = img[b0 + c3], A4 = img[b0 + c4];
    const float B0 = img[b1 + c0], B1 = img[b1 + c1], B2 = img[b1 + c2],
                B3 = img[b1 + c3], B4 = img[b1 + c4];
    const float C0 = img[b2 + c0], C1 = img[b2 + c1], C2 = img[b2 + c2],
                C3 = img[b2 + c3], C4 = img[b2 + c4];
    const float D0 = img[b3 + c0], D1 = img[b3 + c1], D2 = img[b3 + c2],
                D3 = img[b3 + c3], D4 = img[b3 + c4];
    const float E0 = img[b4 + c0], E1 = img[b4 + c1], E2 = img[b4 + c2],
                E3 = img[b4 + c3], E4 = img[b4 + c4];
    const float F0 = img[b5 + c0], F1 = img[b5 + c1], F2 = img[b5 + c2],
                F3 = img[b5 + c3], F4 = img[b5 + c4];

    // shared 20 = rows B..E (yT-1 .. yT+2) x 5 cols -> middle 8
    float u0, u1, u2, u3, u4, u5, u6, u7;
    shared20(B0, B1, B2, B3, B4,
             C0, C1, C2, C3, C4,
             D0, D1, D2, D3, D4,
             E0, E1, E2, E3, E4,
             u0, u1, u2, u3, u4, u5, u6, u7);

    // top pixel (row yT): private row = A (yT-2); bottom (yT+1): private row = F (yT+3)
    const float mT = tail5(u0, u1, u2, u3, u4, u5, u6, u7, A0, A1, A2, A3, A4);
    const float mB = tail5(u0, u1, u2, u3, u4, u5, u6, u7, F0, F1, F2, F3, F4);

    out[b2 + x] = mT;
    out[b3 + x] = mB;
}

extern "C" void kernel_launch(void* const* d_in, const int* in_sizes, int n_in,
                              void* d_out, int out_size, void* d_ws, size_t ws_size,
                              hipStream_t stream) {
    const float* img = (const float*)d_in[0];
    float* out = (float*)d_out;
    dim3 block(64, 4);
    dim3 grid(IMG_W / 64, (IMG_H / 2) / 4);   // 32 x 256 = 8192 blocks
    median5x5_vpair<<<grid, block, 0, stream>>>(img, out);
}

// Round 12
// 22.582 us; speedup vs baseline: 1.1154x; 1.1154x over previous
//
#include <hip/hip_runtime.h>

constexpr int IMG_H = 2048;
constexpr int IMG_W = 2048;
constexpr int P = 4;  // output rows per thread

// compare-exchange: a=min, b=max (2 VALU)
#define CE(a, b) {                                              \
    float _mn, _mx;                                             \
    asm("v_min_f32 %0, %1, %2" : "=v"(_mn) : "v"(a), "v"(b));   \
    asm("v_max_f32 %0, %1, %2" : "=v"(_mx) : "v"(a), "v"(b));   \
    a = _mn; b = _mx;                                           \
}

// 3-element sort via VOP3 3-input ops: a=min, b=med, c=max (3 VALU)
#define SORT3(a, b, c) {                                                      \
    float _n, _d, _x;                                                         \
    asm("v_min3_f32 %0, %1, %2, %3" : "=v"(_n) : "v"(a), "v"(b), "v"(c));     \
    asm("v_med3_f32 %0, %1, %2, %3" : "=v"(_d) : "v"(a), "v"(b), "v"(c));     \
    asm("v_max3_f32 %0, %1, %2, %3" : "=v"(_x) : "v"(a), "v"(b), "v"(c));     \
    a = _n; b = _d; c = _x;                                                   \
}

__device__ __forceinline__ void sw14(float& a0, float& a1, float& a2, float& a3, float& a4,
                                     float& a5, float& a6, float& a7, float& a8, float& a9,
                                     float& a10, float& a11, float& a12, float& a13) {
    SORT3(a0, a1, a2) SORT3(a3, a4, a5) SORT3(a6, a7, a8) SORT3(a9, a10, a11) CE(a12, a13)
    SORT3(a0, a3, a6) SORT3(a0, a9, a12)
    SORT3(a2, a5, a8) SORT3(a8, a11, a13)
}
__device__ __forceinline__ void sw13(float& a0, float& a1, float& a2, float& a3, float& a4,
                                     float& a5, float& a6, float& a7, float& a8, float& a9,
                                     float& a10, float& a11, float& a12) {
    SORT3(a0, a1, a2) SORT3(a3, a4, a5) SORT3(a6, a7, a8) SORT3(a9, a10, a11)
    SORT3(a0, a3, a6) SORT3(a0, a9, a12)
    SORT3(a2, a5, a8) SORT3(a8, a11, a12)
}
__device__ __forceinline__ void sw12(float& a0, float& a1, float& a2, float& a3, float& a4,
                                     float& a5, float& a6, float& a7, float& a8, float& a9,
                                     float& a10, float& a11) {
    SORT3(a0, a1, a2) SORT3(a3, a4, a5) SORT3(a6, a7, a8) SORT3(a9, a10, a11)
    SORT3(a0, a3, a6) CE(a0, a9)
    SORT3(a2, a5, a8) CE(a8, a11)
}
__device__ __forceinline__ void sw11(float& a0, float& a1, float& a2, float& a3, float& a4,
                                     float& a5, float& a6, float& a7, float& a8, float& a9,
                                     float& a10) {
    SORT3(a0, a1, a2) SORT3(a3, a4, a5) SORT3(a6, a7, a8) CE(a9, a10)
    SORT3(a0, a3, a6) CE(a0, a9)
    SORT3(a2, a5, a8) CE(a8, a10)
}
__device__ __forceinline__ void sw10(float& a0, float& a1, float& a2, float& a3, float& a4,
                                     float& a5, float& a6, float& a7, float& a8, float& a9) {
    SORT3(a0, a1, a2) SORT3(a3, a4, a5) SORT3(a6, a7, a8)
    SORT3(a0, a3, a6) CE(a0, a9)
    SORT3(a2, a5, a8) CE(a8, a9)
}
__device__ __forceinline__ void sw9(float& a0, float& a1, float& a2, float& a3, float& a4,
                                    float& a5, float& a6, float& a7, float& a8) {
    SORT3(a0, a1, a2) SORT3(a3, a4, a5) SORT3(a6, a7, a8)
    SORT3(a0, a3, a6)
    SORT3(a2, a5, a8)
}
__device__ __forceinline__ void sw8(float& a0, float& a1, float& a2, float& a3, float& a4,
                                    float& a5, float& a6, float& a7) {
    SORT3(a0, a1, a2) SORT3(a3, a4, a5) CE(a6, a7)
    SORT3(a0, a3, a6)
    SORT3(a2, a5, a7)
}
__device__ __forceinline__ void sw7(float& a0, float& a1, float& a2, float& a3, float& a4,
                                    float& a5, float& a6) {
    SORT3(a0, a1, a2) SORT3(a3, a4, a5)
    SORT3(a0, a3, a6)
    SORT3(a2, a5, a6)
}
__device__ __forceinline__ void sw6(float& a0, float& a1, float& a2, float& a3, float& a4,
                                    float& a5) {
    SORT3(a0, a1, a2) SORT3(a3, a4, a5)
    CE(a0, a3)
    CE(a2, a5)
}

__device__ __forceinline__ float med5(float l0, float l1, float l2, float l3, float l4) {
    CE(l0, l1) CE(l2, l3)
    float a, b;
    asm("v_max_f32 %0, %1, %2" : "=v"(a) : "v"(l0), "v"(l2));
    asm("v_min_f32 %0, %1, %2" : "=v"(b) : "v"(l1), "v"(l3));
    return __builtin_amdgcn_fmed3f(a, b, l4);
}

// tail: 8 shared survivors + 5 private column values -> exact median of 25
__device__ __forceinline__ float tail5(float l1, float l2, float l3, float l4, float l5,
                                       float l6, float l7, float l8,
                                       float p0, float p1, float p2, float p3, float p4) {
    float l0 = p0;
    sw9(l0, l1, l2, l3, l4, l5, l6, l7, l8);
    l0 = p1;
    sw8(l0, l1, l2, l3, l4, l5, l6, l7);
    l0 = p2;
    sw7(l0, l1, l2, l3, l4, l5, l6);
    l0 = p3;
    sw6(l0, l1, l2, l3, l4, l5);
    l0 = p4;
    return med5(l0, l1, l2, l3, l4);
}

// shared forgetful phase over 20 elements (4 shared cols x 5 rows) -> middle 8.
__device__ __forceinline__ void shared20(float s0, float s1, float s2, float s3, float s4,
                                         float s5, float s6, float s7, float s8, float s9,
                                         float s10, float s11, float s12, float s13,
                                         float s14, float s15, float s16, float s17,
                                         float s18, float s19,
                                         float& o0, float& o1, float& o2, float& o3,
                                         float& o4, float& o5, float& o6, float& o7) {
    sw14(s0, s1, s2, s3, s4, s5, s6, s7, s8, s9, s10, s11, s12, s13);
    s0 = s14;
    sw13(s0, s1, s2, s3, s4, s5, s6, s7, s8, s9, s10, s11, s12);
    s0 = s15;
    sw12(s0, s1, s2, s3, s4, s5, s6, s7, s8, s9, s10, s11);
    s0 = s16;
    sw11(s0, s1, s2, s3, s4, s5, s6, s7, s8, s9, s10);
    s0 = s17;
    sw10(s0, s1, s2, s3, s4, s5, s6, s7, s8, s9);
    s0 = s18;
    sw9(s0, s1, s2, s3, s4, s5, s6, s7, s8);
    s0 = s19;
    o0 = s0; o1 = s1; o2 = s2; o3 = s3; o4 = s4; o5 = s5; o6 = s6; o7 = s7;
}

__device__ __forceinline__ int rowbase(int r) {
    r = (r < 0) ? -r : r;
    r = (r >= IMG_H) ? 2 * IMG_H - 2 - r : r;
    return r * IMG_W;
}

// load one window row (6 reflected columns) into named registers R0..R5
#define LOADR(R, rb) {                                        \
    const int _b = (rb);                                      \
    R##0 = img[_b + c0]; R##1 = img[_b + c1];                 \
    R##2 = img[_b + c2]; R##3 = img[_b + c3];                 \
    R##4 = img[_b + c4]; R##5 = img[_b + c5];                 \
}

// one output row: prefetch row (yy)+3 into Rf, compute median row yy from Ra..Re
#define STEP(Ra, Rb, Rc, Rd, Re, Rf, yy) {                                     \
    LOADR(Rf, rowbase((yy) + 3))                                               \
    float u0, u1, u2, u3, u4, u5, u6, u7;                                      \
    shared20(Ra##1, Ra##2, Ra##3, Ra##4, Rb##1, Rb##2, Rb##3, Rb##4,           \
             Rc##1, Rc##2, Rc##3, Rc##4, Rd##1, Rd##2, Rd##3, Rd##4,           \
             Re##1, Re##2, Re##3, Re##4, u0, u1, u2, u3, u4, u5, u6, u7);      \
    const float _mL = tail5(u0, u1, u2, u3, u4, u5, u6, u7,                    \
                            Ra##0, Rb##0, Rc##0, Rd##0, Re##0);                \
    const float _mR = tail5(u0, u1, u2, u3, u4, u5, u6, u7,                    \
                            Ra##5, Rb##5, Rc##5, Rd##5, Re##5);                \
    *reinterpret_cast<float2*>(out + (yy) * IMG_W + xL) = make_float2(_mL, _mR); \
}

__global__ __launch_bounds__(256) void median5x5_strip(const float* __restrict__ img,
                                                       float* __restrict__ out) {
    const int t = blockIdx.x * blockDim.x + threadIdx.x;      // pair-column 0..1023
    const int strip = blockIdx.y * blockDim.y + threadIdx.y;  // 0..511
    const int y0 = strip * P;
    const int xL = 2 * t;

    // reflected column indices xL-2 .. xL+3 (constant over the strip)
    int c0 = xL - 2, c1 = xL - 1, c4 = xL + 2, c5 = xL + 3;
    c0 = (c0 < 0) ? -c0 : c0;
    c1 = (c1 < 0) ? -c1 : c1;
    c4 = (c4 >= IMG_W) ? 2 * IMG_W - 2 - c4 : c4;
    c5 = (c5 >= IMG_W) ? 2 * IMG_W - 2 - c5 : c5;
    const int c2 = xL, c3 = xL + 1;

    // sliding 5-row x 6-col register window across 6 row buffers A..F
    float A0, A1, A2, A3, A4, A5;
    float B0, B1, B2, B3, B4, B5;
    float C0, C1, C2, C3, C4, C5;
    float D0, D1, D2, D3, D4, D5;
    float E0, E1, E2, E3, E4, E5;
    float F0, F1, F2, F3, F4, F5;

    // prologue: rows y0-2 .. y0+2
    LOADR(A, rowbase(y0 - 2))
    LOADR(B, rowbase(y0 - 1))
    LOADR(C, rowbase(y0))
    LOADR(D, rowbase(y0 + 1))
    LOADR(E, rowbase(y0 + 2))

    STEP(A, B, C, D, E, F, y0 + 0)
    STEP(B, C, D, E, F, A, y0 + 1)
    STEP(C, D, E, F, A, B, y0 + 2)
    STEP(D, E, F, A, B, C, y0 + 3)
}

extern "C" void kernel_launch(void* const* d_in, const int* in_sizes, int n_in,
                              void* d_out, int out_size, void* d_ws, size_t ws_size,
                              hipStream_t stream) {
    const float* img = (const float*)d_in[0];
    float* out = (float*)d_out;
    dim3 block(64, 4);
    dim3 grid((IMG_W / 2) / 64, IMG_H / P / 4);   // 16 x 128 = 2048 blocks
    median5x5_strip<<<grid, block, 0, stream>>>(img, out);
}